// Round 7
// baseline (199.096 us; speedup 1.0000x reference)
//
#include <hip/hip_runtime.h>

// MSDeformAttn: B=4, Lq=Lv=5440 (M=21760), C=256, heads=8, levels=4, points=4, hd=32
// Level shapes: (64,64),(32,32),(16,16),(8,8) -> starts 0,4096,5120,5376
//
// R6: fuse GEMM3 into the sampler (launch-count attack, standard launches).
//  - R5 cooperative launch failed (no output -> launch rejected); reverted.
//  - R2-R4 evidence: non-sampler cost ~138us across 3 structures, each dispatch
//    <47us and ~work-independent (~45us each) -> remove dispatches by fusion.
//  - sample_out: block = 16 queries; phase A samples into LDS (16x264 f16,
//    pitch 264 -> conflict-free), phase B = 16x256 out-tile MFMA with A from
//    LDS, B (wto) direct from L2. Kills gemm_single + 22MB acc16 round-trip.
//  - prep_cvt / gemm12 byte-identical to R4 for attribution.

typedef __attribute__((ext_vector_type(8))) _Float16 half8;
typedef __attribute__((ext_vector_type(4))) float f32x4;

typedef __attribute__((address_space(3))) unsigned int lds_uint;
typedef const __attribute__((address_space(1))) unsigned int g_uint;

__device__ __forceinline__ void load_lds16(const _Float16* g, _Float16* l) {
    __builtin_amdgcn_global_load_lds((g_uint*)g, (lds_uint*)l, 16, 0, 0);
}

__device__ __forceinline__ half8 splat8(_Float16 v) {
    half8 r = {v, v, v, v, v, v, v, v};
    return r;
}

#define M_TOTAL 21760

// -------- fused weight prep (transpose+cvt+concat) and value/query f32->f16 ----
__global__ __launch_bounds__(256) void prep_cvt(
    const float* __restrict__ W_val, const float* __restrict__ W_off,
    const float* __restrict__ W_attn, const float* __restrict__ W_out,
    const float* __restrict__ b_off, const float* __restrict__ b_attn,
    const float* __restrict__ value, const float* __restrict__ query,
    _Float16* __restrict__ wt_val, _Float16* __restrict__ wt_qcat,
    _Float16* __restrict__ wt_out, float* __restrict__ bcat,
    _Float16* __restrict__ val16, _Float16* __restrict__ q16)
{
    const int r = blockIdx.x;
    const int k = threadIdx.x;
    if (r < 897) {
        if (r < 256) {
            wt_val[r * 256 + k] = (_Float16)W_val[k * 256 + r];
        } else if (r < 640) {
            const int n = r - 256;
            const float v = (n < 256) ? W_off[k * 256 + n] : W_attn[k * 128 + (n - 256)];
            wt_qcat[n * 256 + k] = (_Float16)v;
        } else if (r < 896) {
            const int n = r - 640;
            wt_out[n * 256 + k] = (_Float16)W_out[k * 256 + n];
        } else {
            bcat[k] = b_off[k];
            if (k < 128) bcat[256 + k] = b_attn[k];
        }
        return;
    }
    const size_t per = (size_t)M_TOTAL * 256 / 8;
    size_t idx = (size_t)(r - 897) * 256 + k;
    const float* src;
    _Float16* dst;
    if (idx < per) { src = value; dst = val16; }
    else { src = query; dst = q16; idx -= per; }
    const float4 lo = *(const float4*)(src + idx * 8);
    const float4 hi = *(const float4*)(src + idx * 8 + 4);
    half8 o = {(_Float16)lo.x, (_Float16)lo.y, (_Float16)lo.z, (_Float16)lo.w,
               (_Float16)hi.x, (_Float16)hi.y, (_Float16)hi.z, (_Float16)hi.w};
    *(half8*)(dst + idx * 8) = o;
}

// -------- f16 MFMA GEMM core: C[128x64 tile] = A[M,256] * Bt[NN,256]^T + bias --
// 4 waves as 2x2, wave tile 64x32 (4x2 MFMAs of 16x16x32). BK=32, DMA staging.
__device__ __forceinline__ void gemm_core(
    const _Float16* __restrict__ A, const _Float16* __restrict__ Bt,
    const float* __restrict__ bias, void* __restrict__ Cv,
    int NN, int outf16, int mt, int nt)
{
    __shared__ _Float16 Ah[128 * 32];
    __shared__ _Float16 Bh[64 * 32];

    const int tid = threadIdx.x;
    const int bm = mt * 128;
    const int bn = nt * 64;
    const int wave = tid >> 6, lane = tid & 63;
    const int wm = (wave & 1) * 64, wn = (wave >> 1) * 32;
    const int ml = lane & 15, kq = (lane >> 4) * 8;
    const int lr = lane >> 2;          // staging row within 16-row chunk
    const int lk = (lane & 3) * 8;     // staging k offset (f16)

    const f32x4 zero4 = {0.f, 0.f, 0.f, 0.f};
    f32x4 acc[4][2];
#pragma unroll
    for (int i = 0; i < 4; ++i)
#pragma unroll
        for (int j = 0; j < 2; ++j) acc[i][j] = zero4;

    for (int kt = 0; kt < 8; ++kt) {
        const int k0 = kt * 32;
        __syncthreads();
#pragma unroll
        for (int t = 0; t < 2; ++t) {
            const int row = wave * 32 + t * 16;
            load_lds16(A + (size_t)(bm + row + lr) * 256 + k0 + lk,
                       Ah + (size_t)row * 32);
        }
        {
            const int row = wave * 16;
            load_lds16(Bt + (size_t)(bn + row + lr) * 256 + k0 + lk,
                       Bh + (size_t)row * 32);
        }
        __syncthreads();

        half8 af[4], bf[2];
#pragma unroll
        for (int i = 0; i < 4; ++i)
            af[i] = *(const half8*)(Ah + (wm + i * 16 + ml) * 32 + kq);
#pragma unroll
        for (int j = 0; j < 2; ++j)
            bf[j] = *(const half8*)(Bh + (wn + j * 16 + ml) * 32 + kq);
#pragma unroll
        for (int i = 0; i < 4; ++i)
#pragma unroll
            for (int j = 0; j < 2; ++j)
                acc[i][j] = __builtin_amdgcn_mfma_f32_16x16x32_f16(af[i], bf[j], acc[i][j], 0, 0, 0);
    }

    const int r0 = (lane >> 4) * 4;
#pragma unroll
    for (int j = 0; j < 2; ++j) {
        const int col = bn + wn + j * 16 + ml;
        const float bj = bias[col];
#pragma unroll
        for (int i = 0; i < 4; ++i) {
            const size_t rbase = (size_t)(bm + wm + i * 16 + r0) * NN + col;
#pragma unroll
            for (int r = 0; r < 4; ++r) {
                const float v = acc[i][j][r] + bj;
                if (outf16)
                    ((_Float16*)Cv)[rbase + (size_t)r * NN] = (_Float16)v;
                else
                    ((float*)Cv)[rbase + (size_t)r * NN] = v;
            }
        }
    }
}

// GEMM1 (val16*wtv->valh, 680 tiles) + GEMM2 (q16*wtq->offh, 1020 tiles)
__global__ __launch_bounds__(256) void gemm12(
    const _Float16* __restrict__ val16, const _Float16* __restrict__ q16,
    const _Float16* __restrict__ wtv, const _Float16* __restrict__ wtq,
    const float* __restrict__ b_val, const float* __restrict__ bcat,
    _Float16* __restrict__ valh, _Float16* __restrict__ offh)
{
    int id = blockIdx.x;
    if (id < 680) {
        gemm_core(val16, wtv, b_val, valh, 256, 1, id >> 2, id & 3);
    } else {
        id -= 680;
        gemm_core(q16, wtq, bcat, offh, 384, 1, (id - 0) / 6, (id - 0) % 6);
    }
}

// ---------- fused sampler + output GEMM: block = 16 queries --------------------
// Phase A: sample 16 queries (2 passes x 8) into LDS accL[16][264] f16.
// Phase B: out[16x256] = accL @ wto^T + b_out, A-frags from LDS, B from global.
__global__ __launch_bounds__(256) void sample_out(
    const _Float16* __restrict__ valh,   // [M,256] f16
    const float* __restrict__ refp,      // [B,Lq,4,2]
    const _Float16* __restrict__ offh,   // [M,384] f16: 0-255 offsets, 256-383 logits
    const _Float16* __restrict__ wto,    // [256,256] f16 (n-major, k-contig)
    const float* __restrict__ b_out,
    float* __restrict__ out)             // [M,256] f32
{
    __shared__ _Float16 accL[16 * 264];  // pitch 264 f16 = 528B -> bank shift 4

    const int q0 = blockIdx.x * 16;
    const int wave = threadIdx.x >> 6, lane = threadIdx.x & 63;
    const int q2 = lane >> 5, sl = lane & 31;
    const int h = sl >> 2;          // head
    const int d8 = (sl & 3) * 8;    // channel octet within head

    const int Ws_[4] = {64, 32, 16, 8};
    const int starts_[4] = {0, 4096, 5120, 5376};

    // ---- phase A: sampling ----
    for (int pass = 0; pass < 2; ++pass) {
        const int ql = pass * 8 + wave * 2 + q2;
        const int bq = q0 + ql;
        const int b = bq / 5440;

        const _Float16* off_row = offh + (size_t)bq * 384 + h * 32;
        const _Float16* att_row = offh + (size_t)bq * 384 + 256 + h * 16;
        const float* rp = refp + (size_t)bq * 8;

        float offv[32];
#pragma unroll
        for (int i = 0; i < 4; ++i) {
            const half8 t = *(const half8*)(off_row + i * 8);
#pragma unroll
            for (int j = 0; j < 8; ++j) offv[i * 8 + j] = (float)t[j];
        }
        float lg[16];
        {
            const half8 t0 = *(const half8*)(att_row);
            const half8 t1 = *(const half8*)(att_row + 8);
#pragma unroll
            for (int j = 0; j < 8; ++j) { lg[j] = (float)t0[j]; lg[8 + j] = (float)t1[j]; }
        }
        float mx = -1e30f;
#pragma unroll
        for (int i = 0; i < 16; ++i) mx = fmaxf(mx, lg[i]);
        float s = 0.f;
#pragma unroll
        for (int i = 0; i < 16; ++i) { lg[i] = __expf(lg[i] - mx); s += lg[i]; }
        const float inv = 1.f / s;

        const float4 rp01 = *(const float4*)rp;
        const float4 rp23 = *(const float4*)(rp + 4);
        const float rxs[4] = {rp01.x, rp01.z, rp23.x, rp23.z};
        const float rys[4] = {rp01.y, rp01.w, rp23.y, rp23.w};

        half8 acc = splat8((_Float16)0.f);
#pragma unroll
        for (int l = 0; l < 4; ++l) {
            const int W = Ws_[l];
            const float fW = (float)W;
            const _Float16* vbase = valh + ((size_t)(b * 5440 + starts_[l])) * 256 + h * 32 + d8;
            const float rx = rxs[l], ry = rys[l];
#pragma unroll
            for (int p = 0; p < 4; ++p) {
                const int pi = l * 4 + p;
                const float aw = lg[pi] * inv;
                const float x = fmaf(rx, fW, offv[pi * 2 + 0]) - 0.5f;
                const float y = fmaf(ry, fW, offv[pi * 2 + 1]) - 0.5f;
                const float x0f = floorf(x), y0f = floorf(y);
                const int x0 = (int)x0f, y0 = (int)y0f;
                const float wx = x - x0f, wy = y - y0f;
                const bool okx0 = ((unsigned)x0 < (unsigned)W);
                const bool okx1 = ((unsigned)(x0 + 1) < (unsigned)W);
                const bool oky0 = ((unsigned)y0 < (unsigned)W);
                const bool oky1 = ((unsigned)(y0 + 1) < (unsigned)W);
                const int xc0 = min(max(x0, 0), W - 1);
                const int xc1 = min(max(x0 + 1, 0), W - 1);
                const int yc0 = min(max(y0, 0), W - 1);
                const int yc1 = min(max(y0 + 1, 0), W - 1);
                const float w00 = (okx0 & oky0) ? (1.f - wx) * (1.f - wy) * aw : 0.f;
                const float w10 = (okx1 & oky0) ? wx * (1.f - wy) * aw : 0.f;
                const float w01 = (okx0 & oky1) ? (1.f - wx) * wy * aw : 0.f;
                const float w11 = (okx1 & oky1) ? wx * wy * aw : 0.f;

                const half8 c00 = *(const half8*)(vbase + (size_t)(yc0 * W + xc0) * 256);
                const half8 c10 = *(const half8*)(vbase + (size_t)(yc0 * W + xc1) * 256);
                const half8 c01 = *(const half8*)(vbase + (size_t)(yc1 * W + xc0) * 256);
                const half8 c11 = *(const half8*)(vbase + (size_t)(yc1 * W + xc1) * 256);

                acc += c00 * splat8((_Float16)w00);
                acc += c10 * splat8((_Float16)w10);
                acc += c01 * splat8((_Float16)w01);
                acc += c11 * splat8((_Float16)w11);
            }
        }

        *(half8*)(accL + ql * 264 + h * 32 + d8) = acc;
    }

    __syncthreads();

    // ---- phase B: out-tile GEMM. wave w -> cols [w*64, w*64+64) ----
    const int ml = lane & 15, kq = (lane >> 4) * 8;
    const f32x4 zero4 = {0.f, 0.f, 0.f, 0.f};
    f32x4 acc3[4] = {zero4, zero4, zero4, zero4};
#pragma unroll
    for (int kt = 0; kt < 8; ++kt) {
        const half8 af = *(const half8*)(accL + ml * 264 + kt * 32 + kq);
#pragma unroll
        for (int j = 0; j < 4; ++j) {
            const half8 bf = *(const half8*)(wto + (size_t)(wave * 64 + j * 16 + ml) * 256 + kt * 32 + kq);
            acc3[j] = __builtin_amdgcn_mfma_f32_16x16x32_f16(af, bf, acc3[j], 0, 0, 0);
        }
    }
    const int r0 = (lane >> 4) * 4;
#pragma unroll
    for (int j = 0; j < 4; ++j) {
        const int col = wave * 64 + j * 16 + ml;
        const float bj = b_out[col];
#pragma unroll
        for (int r = 0; r < 4; ++r)
            out[(size_t)(q0 + r0 + r) * 256 + col] = acc3[j][r] + bj;
    }
}

extern "C" void kernel_launch(void* const* d_in, const int* in_sizes, int n_in,
                              void* d_out, int out_size, void* d_ws, size_t ws_size,
                              hipStream_t stream) {
    const float* query  = (const float*)d_in[0];
    const float* refp   = (const float*)d_in[1];
    const float* value  = (const float*)d_in[2];
    const float* W_off  = (const float*)d_in[3];
    const float* b_off  = (const float*)d_in[4];
    const float* W_attn = (const float*)d_in[5];
    const float* b_attn = (const float*)d_in[6];
    const float* W_val  = (const float*)d_in[7];
    const float* b_val  = (const float*)d_in[8];
    const float* W_out  = (const float*)d_in[9];
    const float* b_out  = (const float*)d_in[10];
    float* out = (float*)d_out;

    const size_t M = M_TOTAL;

    _Float16* val16 = (_Float16*)d_ws;                // M*256
    _Float16* q16   = val16 + M * 256;                // M*256
    _Float16* valh  = q16 + M * 256;                  // M*256
    _Float16* offh  = valh + M * 256;                 // M*384
    _Float16* wtv   = offh + M * 384;                 // 256*256
    _Float16* wtq   = wtv + 256 * 256;                // 384*256
    _Float16* wto   = wtq + 384 * 256;                // 256*256
    float* bcat     = (float*)(wto + 256 * 256);      // 384

    dim3 blk(256);
    prep_cvt<<<dim3(897 + 5440), blk, 0, stream>>>(
        W_val, W_off, W_attn, W_out, b_off, b_attn, value, query,
        wtv, wtq, wto, bcat, val16, q16);
    gemm12<<<dim3(1700), blk, 0, stream>>>(val16, q16, wtv, wtq, b_val, bcat, valh, offh);
    sample_out<<<dim3(M / 16), blk, 0, stream>>>(valh, refp, offh, wto, b_out, out);
}

// Round 8
// 187.703 us; speedup vs baseline: 1.0607x; 1.0607x over previous
//
#include <hip/hip_runtime.h>

// MSDeformAttn: B=4, Lq=Lv=5440 (M=21760), C=256, heads=8, levels=4, points=4, hd=32
// Level shapes: (64,64),(32,32),(16,16),(8,8) -> starts 0,4096,5120,5376
//
// R7: delete the prep/val16/q16 chain.
//  - R6 isolated the cost: prep_cvt+gemm12 = 124us (roofline ~45), gemm_single
//    = 14us (at roofline). The f32->f16 convert round-trip + prep pass is the
//    elephant, not a per-dispatch floor.
//  - gemm12_cvt: GEMM1+GEMM2 direct from f32 (A: float4+cvt staging; B:
//    transpose-cvt from f32 W_* per tile; bias inline). LDS pitch 34 (17 dw,
//    coprime 32) -> <=2-way bank conflicts.
//  - sampler = R4 standalone (47us known); first 256 blocks also transpose
//    W_out -> wto f16 (consumed by next dispatch only).
//  - gemm_single byte-identical to R4 (14us known).

typedef __attribute__((ext_vector_type(8))) _Float16 half8;
typedef __attribute__((ext_vector_type(4))) float f32x4;

typedef __attribute__((address_space(3))) unsigned int lds_uint;
typedef const __attribute__((address_space(1))) unsigned int g_uint;

__device__ __forceinline__ void load_lds16(const _Float16* g, _Float16* l) {
    __builtin_amdgcn_global_load_lds((g_uint*)g, (lds_uint*)l, 16, 0, 0);
}

__device__ __forceinline__ half8 splat8(_Float16 v) {
    half8 r = {v, v, v, v, v, v, v, v};
    return r;
}

#define M_TOTAL 21760

// -------- fused GEMM1+GEMM2 from f32 sources, 128x64 tiles, BK=32 -------------
// C[M,NN] = A_f32[M,256] @ W_f32[256,NN] + bias, output f16 (row-major).
// 4 waves as 2x2, wave tile 64x32 (4x2 MFMAs of 16x16x32).
__global__ __launch_bounds__(256) void gemm12_cvt(
    const float* __restrict__ value, const float* __restrict__ query,
    const float* __restrict__ W_val, const float* __restrict__ W_off,
    const float* __restrict__ W_attn,
    const float* __restrict__ b_val, const float* __restrict__ b_off,
    const float* __restrict__ b_attn,
    _Float16* __restrict__ valh, _Float16* __restrict__ offh)
{
    __shared__ _Float16 As[128 * 34];   // pitch 34 f16 = 17 dwords (coprime 32)
    __shared__ _Float16 Bs[64 * 34];

    const bool g1 = blockIdx.x < 680;
    const int id = g1 ? blockIdx.x : blockIdx.x - 680;
    const int mt = g1 ? (id >> 2) : (id / 6);
    const int nt = g1 ? (id & 3) : (id % 6);
    const int NN = g1 ? 256 : 384;
    const float* A = g1 ? value : query;
    _Float16* C = g1 ? valh : offh;
    const int bm = mt * 128;
    const int bn = nt * 64;

    // B source: W[(k)*sW + nb + n] for tile cols n in [0,64)
    const float* W;
    int sW, nb;
    if (g1)           { W = W_val;  sW = 256; nb = bn; }
    else if (bn < 256){ W = W_off;  sW = 256; nb = bn; }
    else              { W = W_attn; sW = 128; nb = bn - 256; }

    const int tid = threadIdx.x;
    const int wave = tid >> 6, lane = tid & 63;
    const int wm = (wave & 1) * 64, wn = (wave >> 1) * 32;
    const int ml = lane & 15, kq = (lane >> 4) * 8;

    // A staging: thread -> row = tid>>1 (0..127), kb = (tid&1)*16
    const int ar = tid >> 1, akb = (tid & 1) * 16;
    // B staging: thread -> n = tid&63, k8 = (tid>>6)*8
    const int bn_l = tid & 63, bk8 = (tid >> 6) * 8;

    const f32x4 zero4 = {0.f, 0.f, 0.f, 0.f};
    f32x4 acc[4][2];
#pragma unroll
    for (int i = 0; i < 4; ++i)
#pragma unroll
        for (int j = 0; j < 2; ++j) acc[i][j] = zero4;

    for (int kt = 0; kt < 8; ++kt) {
        const int k0 = kt * 32;
        // loads to regs (issued before barrier -> prefetch across prior compute)
        const float* as = A + (size_t)(bm + ar) * 256 + k0 + akb;
        const float4 a0 = *(const float4*)(as + 0);
        const float4 a1 = *(const float4*)(as + 4);
        const float4 a2 = *(const float4*)(as + 8);
        const float4 a3 = *(const float4*)(as + 12);
        float bv[8];
#pragma unroll
        for (int j = 0; j < 8; ++j)
            bv[j] = W[(size_t)(k0 + bk8 + j) * sW + nb + bn_l];

        const half8 ha0 = {(_Float16)a0.x, (_Float16)a0.y, (_Float16)a0.z, (_Float16)a0.w,
                           (_Float16)a1.x, (_Float16)a1.y, (_Float16)a1.z, (_Float16)a1.w};
        const half8 ha1 = {(_Float16)a2.x, (_Float16)a2.y, (_Float16)a2.z, (_Float16)a2.w,
                           (_Float16)a3.x, (_Float16)a3.y, (_Float16)a3.z, (_Float16)a3.w};
        const half8 hb = {(_Float16)bv[0], (_Float16)bv[1], (_Float16)bv[2], (_Float16)bv[3],
                          (_Float16)bv[4], (_Float16)bv[5], (_Float16)bv[6], (_Float16)bv[7]};

        __syncthreads();   // prior tile's LDS reads complete
        *(half8*)(As + ar * 34 + akb) = ha0;
        *(half8*)(As + ar * 34 + akb + 8) = ha1;
        *(half8*)(Bs + bn_l * 34 + bk8) = hb;
        __syncthreads();   // staging visible

        half8 af[4], bf[2];
#pragma unroll
        for (int i = 0; i < 4; ++i)
            af[i] = *(const half8*)(As + (wm + i * 16 + ml) * 34 + kq);
#pragma unroll
        for (int j = 0; j < 2; ++j)
            bf[j] = *(const half8*)(Bs + (wn + j * 16 + ml) * 34 + kq);
#pragma unroll
        for (int i = 0; i < 4; ++i)
#pragma unroll
            for (int j = 0; j < 2; ++j)
                acc[i][j] = __builtin_amdgcn_mfma_f32_16x16x32_f16(af[i], bf[j], acc[i][j], 0, 0, 0);
    }

    const int r0 = (lane >> 4) * 4;
#pragma unroll
    for (int j = 0; j < 2; ++j) {
        const int col = bn + wn + j * 16 + ml;
        const float bj = g1 ? b_val[col] : (col < 256 ? b_off[col] : b_attn[col - 256]);
#pragma unroll
        for (int i = 0; i < 4; ++i) {
            const size_t rbase = (size_t)(bm + wm + i * 16 + r0) * NN + col;
#pragma unroll
            for (int r = 0; r < 4; ++r)
                C[rbase + (size_t)r * NN] = (_Float16)(acc[i][j][r] + bj);
        }
    }
}

// -------- R4 GEMM core (DMA staging, pitch 32) for the final GEMM -------------
__device__ __forceinline__ void gemm_core(
    const _Float16* __restrict__ A, const _Float16* __restrict__ Bt,
    const float* __restrict__ bias, float* __restrict__ Cv,
    int NN, int mt, int nt)
{
    __shared__ _Float16 Ah[128 * 32];
    __shared__ _Float16 Bh[64 * 32];

    const int tid = threadIdx.x;
    const int bm = mt * 128;
    const int bn = nt * 64;
    const int wave = tid >> 6, lane = tid & 63;
    const int wm = (wave & 1) * 64, wn = (wave >> 1) * 32;
    const int ml = lane & 15, kq = (lane >> 4) * 8;
    const int lr = lane >> 2;
    const int lk = (lane & 3) * 8;

    const f32x4 zero4 = {0.f, 0.f, 0.f, 0.f};
    f32x4 acc[4][2];
#pragma unroll
    for (int i = 0; i < 4; ++i)
#pragma unroll
        for (int j = 0; j < 2; ++j) acc[i][j] = zero4;

    for (int kt = 0; kt < 8; ++kt) {
        const int k0 = kt * 32;
        __syncthreads();
#pragma unroll
        for (int t = 0; t < 2; ++t) {
            const int row = wave * 32 + t * 16;
            load_lds16(A + (size_t)(bm + row + lr) * 256 + k0 + lk,
                       Ah + (size_t)row * 32);
        }
        {
            const int row = wave * 16;
            load_lds16(Bt + (size_t)(bn + row + lr) * 256 + k0 + lk,
                       Bh + (size_t)row * 32);
        }
        __syncthreads();

        half8 af[4], bf[2];
#pragma unroll
        for (int i = 0; i < 4; ++i)
            af[i] = *(const half8*)(Ah + (wm + i * 16 + ml) * 32 + kq);
#pragma unroll
        for (int j = 0; j < 2; ++j)
            bf[j] = *(const half8*)(Bh + (wn + j * 16 + ml) * 32 + kq);
#pragma unroll
        for (int i = 0; i < 4; ++i)
#pragma unroll
            for (int j = 0; j < 2; ++j)
                acc[i][j] = __builtin_amdgcn_mfma_f32_16x16x32_f16(af[i], bf[j], acc[i][j], 0, 0, 0);
    }

    const int r0 = (lane >> 4) * 4;
#pragma unroll
    for (int j = 0; j < 2; ++j) {
        const int col = bn + wn + j * 16 + ml;
        const float bj = bias[col];
#pragma unroll
        for (int i = 0; i < 4; ++i) {
            const size_t rbase = (size_t)(bm + wm + i * 16 + r0) * NN + col;
#pragma unroll
            for (int r = 0; r < 4; ++r)
                Cv[rbase + (size_t)r * NN] = acc[i][j][r] + bj;
        }
    }
}

__global__ __launch_bounds__(256) void gemm_single(
    const _Float16* __restrict__ A, const _Float16* __restrict__ Bt,
    const float* __restrict__ bias, float* __restrict__ Cv)
{
    const int id = blockIdx.x;
    gemm_core(A, Bt, bias, Cv, 256, id >> 2, id & 3);
}

// ---------------- sampler (R4-identical) + embedded wto transpose -------------
__global__ __launch_bounds__(256) void sample_f16(
    const _Float16* __restrict__ valh,   // [M,256] f16
    const float* __restrict__ refp,      // [B,Lq,4,2]
    const _Float16* __restrict__ offh,   // [M,384] f16: 0-255 offsets, 256-383 logits
    const float* __restrict__ W_out,     // [256,256] f32 (k-major)
    _Float16* __restrict__ wto,          // [256,256] f16 (n-major, k-contig)
    _Float16* __restrict__ acc_out)      // [M,256] f16
{
    // fold W_out transpose into the first 256 blocks (consumed next dispatch)
    if (blockIdx.x < 256)
        wto[blockIdx.x * 256 + threadIdx.x] =
            (_Float16)W_out[threadIdx.x * 256 + blockIdx.x];

    const int wave = threadIdx.x >> 6, lane = threadIdx.x & 63;
    const int q2 = lane >> 5, sl = lane & 31;
    const int bq = blockIdx.x * 8 + wave * 2 + q2;    // 0..21759
    const int b = bq / 5440;
    const int h = sl >> 2;          // head
    const int d8 = (sl & 3) * 8;    // channel octet within head

    const _Float16* off_row = offh + (size_t)bq * 384 + h * 32;
    const _Float16* att_row = offh + (size_t)bq * 384 + 256 + h * 16;
    const float* rp = refp + (size_t)bq * 8;

    float offv[32];
#pragma unroll
    for (int i = 0; i < 4; ++i) {
        const half8 t = *(const half8*)(off_row + i * 8);
#pragma unroll
        for (int j = 0; j < 8; ++j) offv[i * 8 + j] = (float)t[j];
    }
    float lg[16];
    {
        const half8 t0 = *(const half8*)(att_row);
        const half8 t1 = *(const half8*)(att_row + 8);
#pragma unroll
        for (int j = 0; j < 8; ++j) { lg[j] = (float)t0[j]; lg[8 + j] = (float)t1[j]; }
    }
    float mx = -1e30f;
#pragma unroll
    for (int i = 0; i < 16; ++i) mx = fmaxf(mx, lg[i]);
    float s = 0.f;
#pragma unroll
    for (int i = 0; i < 16; ++i) { lg[i] = __expf(lg[i] - mx); s += lg[i]; }
    const float inv = 1.f / s;

    const float4 rp01 = *(const float4*)rp;
    const float4 rp23 = *(const float4*)(rp + 4);
    const float rxs[4] = {rp01.x, rp01.z, rp23.x, rp23.z};
    const float rys[4] = {rp01.y, rp01.w, rp23.y, rp23.w};

    const int Ws_[4] = {64, 32, 16, 8};
    const int starts_[4] = {0, 4096, 5120, 5376};

    half8 acc = splat8((_Float16)0.f);
#pragma unroll
    for (int l = 0; l < 4; ++l) {
        const int W = Ws_[l];
        const float fW = (float)W;
        const _Float16* vbase = valh + ((size_t)(b * 5440 + starts_[l])) * 256 + h * 32 + d8;
        const float rx = rxs[l], ry = rys[l];
#pragma unroll
        for (int p = 0; p < 4; ++p) {
            const int pi = l * 4 + p;
            const float aw = lg[pi] * inv;
            const float x = fmaf(rx, fW, offv[pi * 2 + 0]) - 0.5f;
            const float y = fmaf(ry, fW, offv[pi * 2 + 1]) - 0.5f;
            const float x0f = floorf(x), y0f = floorf(y);
            const int x0 = (int)x0f, y0 = (int)y0f;
            const float wx = x - x0f, wy = y - y0f;
            const bool okx0 = ((unsigned)x0 < (unsigned)W);
            const bool okx1 = ((unsigned)(x0 + 1) < (unsigned)W);
            const bool oky0 = ((unsigned)y0 < (unsigned)W);
            const bool oky1 = ((unsigned)(y0 + 1) < (unsigned)W);
            const int xc0 = min(max(x0, 0), W - 1);
            const int xc1 = min(max(x0 + 1, 0), W - 1);
            const int yc0 = min(max(y0, 0), W - 1);
            const int yc1 = min(max(y0 + 1, 0), W - 1);
            const float w00 = (okx0 & oky0) ? (1.f - wx) * (1.f - wy) * aw : 0.f;
            const float w10 = (okx1 & oky0) ? wx * (1.f - wy) * aw : 0.f;
            const float w01 = (okx0 & oky1) ? (1.f - wx) * wy * aw : 0.f;
            const float w11 = (okx1 & oky1) ? wx * wy * aw : 0.f;

            const half8 c00 = *(const half8*)(vbase + (size_t)(yc0 * W + xc0) * 256);
            const half8 c10 = *(const half8*)(vbase + (size_t)(yc0 * W + xc1) * 256);
            const half8 c01 = *(const half8*)(vbase + (size_t)(yc1 * W + xc0) * 256);
            const half8 c11 = *(const half8*)(vbase + (size_t)(yc1 * W + xc1) * 256);

            acc += c00 * splat8((_Float16)w00);
            acc += c10 * splat8((_Float16)w10);
            acc += c01 * splat8((_Float16)w01);
            acc += c11 * splat8((_Float16)w11);
        }
    }

    *(half8*)(acc_out + (size_t)bq * 256 + h * 32 + d8) = acc;
}

extern "C" void kernel_launch(void* const* d_in, const int* in_sizes, int n_in,
                              void* d_out, int out_size, void* d_ws, size_t ws_size,
                              hipStream_t stream) {
    const float* query  = (const float*)d_in[0];
    const float* refp   = (const float*)d_in[1];
    const float* value  = (const float*)d_in[2];
    const float* W_off  = (const float*)d_in[3];
    const float* b_off  = (const float*)d_in[4];
    const float* W_attn = (const float*)d_in[5];
    const float* b_attn = (const float*)d_in[6];
    const float* W_val  = (const float*)d_in[7];
    const float* b_val  = (const float*)d_in[8];
    const float* W_out  = (const float*)d_in[9];
    const float* b_out  = (const float*)d_in[10];
    float* out = (float*)d_out;

    const size_t M = M_TOTAL;

    _Float16* valh  = (_Float16*)d_ws;                // M*256
    _Float16* offh  = valh + M * 256;                 // M*384
    _Float16* acc16 = offh + M * 384;                 // M*256
    _Float16* wto   = acc16 + M * 256;                // 256*256

    dim3 blk(256);
    gemm12_cvt<<<dim3(1700), blk, 0, stream>>>(
        value, query, W_val, W_off, W_attn, b_val, b_off, b_attn, valh, offh);
    sample_f16<<<dim3(M / 8), blk, 0, stream>>>(valh, refp, offh, W_out, wto, acc16);
    gemm_single<<<dim3(680), blk, 0, stream>>>(acc16, wto, b_out, out);
}

// Round 9
// 180.061 us; speedup vs baseline: 1.1057x; 1.0424x over previous
//
#include <hip/hip_runtime.h>

// MSDeformAttn: B=4, Lq=Lv=5440 (M=21760), C=256, heads=8, levels=4, points=4, hd=32
// Level shapes: (64,64),(32,32),(16,16),(8,8) -> starts 0,4096,5120,5376
//
// R8: sampler load-latency attack + gemm12 A-traffic halving.
//  - R7 post-mortem: all GEMM dispatches <48us (never in top-5); totals imply
//    ~70-80us invariant harness/replay overhead. Actionable budget = kernel
//    bodies; sampler (48us, VGPR=40) is latency-bound: ~4 outstanding gathers.
//  - sampler: batch all 16 corner loads of a level into c_[16] (64 VGPR in
//    flight), launch_bounds(256,4) for VGPR headroom. Predict 48 -> ~32us.
//  - gemm12_cvt: BN 64->128 -> A passes 4+6 -> 2+3 (223 -> 111 MB).
//  - gemm_single unchanged (R4 core, ~15us).

typedef __attribute__((ext_vector_type(8))) _Float16 half8;
typedef __attribute__((ext_vector_type(4))) float f32x4;

typedef __attribute__((address_space(3))) unsigned int lds_uint;
typedef const __attribute__((address_space(1))) unsigned int g_uint;

__device__ __forceinline__ void load_lds16(const _Float16* g, _Float16* l) {
    __builtin_amdgcn_global_load_lds((g_uint*)g, (lds_uint*)l, 16, 0, 0);
}

__device__ __forceinline__ half8 splat8(_Float16 v) {
    half8 r = {v, v, v, v, v, v, v, v};
    return r;
}

#define M_TOTAL 21760

// -------- fused GEMM1+GEMM2 from f32 sources, 128x128 tiles, BK=32 ------------
// GEMM1: valh[M,256] = value @ W_val + b_val   (340 tiles: 170m x 2n)
// GEMM2: offh[M,384] = query @ [W_off|W_attn] + [b_off|b_attn] (510: 170m x 3n)
// 4 waves as 2x2, wave tile 64x64 (4x4 MFMAs of 16x16x32).
__global__ __launch_bounds__(256) void gemm12_cvt(
    const float* __restrict__ value, const float* __restrict__ query,
    const float* __restrict__ W_val, const float* __restrict__ W_off,
    const float* __restrict__ W_attn,
    const float* __restrict__ b_val, const float* __restrict__ b_off,
    const float* __restrict__ b_attn,
    _Float16* __restrict__ valh, _Float16* __restrict__ offh)
{
    __shared__ _Float16 As[128 * 34];   // pitch 34 f16 = 17 dwords (coprime 32)
    __shared__ _Float16 Bs[128 * 34];

    const bool g1 = blockIdx.x < 340;
    const int id = g1 ? blockIdx.x : blockIdx.x - 340;
    const int mt = g1 ? (id >> 1) : (id / 3);
    const int nt = g1 ? (id & 1) : (id % 3);
    const int NN = g1 ? 256 : 384;
    const float* A = g1 ? value : query;
    _Float16* C = g1 ? valh : offh;
    const int bm = mt * 128;
    const int bn = nt * 128;

    // B source: W[k*sW + nb + n] for tile cols n in [0,128)
    const float* W;
    int sW, nb;
    if (g1)            { W = W_val;  sW = 256; nb = bn; }
    else if (nt < 2)   { W = W_off;  sW = 256; nb = bn; }
    else               { W = W_attn; sW = 128; nb = 0;  }

    const int tid = threadIdx.x;
    const int wave = tid >> 6, lane = tid & 63;
    const int wm = (wave & 1) * 64, wn = (wave >> 1) * 64;
    const int ml = lane & 15, kq = (lane >> 4) * 8;

    // A staging: thread -> row = tid>>1 (0..127), kb = (tid&1)*16
    const int ar = tid >> 1, akb = (tid & 1) * 16;
    // B staging: thread -> n = tid&127, k group = (tid>>7)*16
    const int bn_l = tid & 127, bkg = (tid >> 7) * 16;

    const f32x4 zero4 = {0.f, 0.f, 0.f, 0.f};
    f32x4 acc[4][4];
#pragma unroll
    for (int i = 0; i < 4; ++i)
#pragma unroll
        for (int j = 0; j < 4; ++j) acc[i][j] = zero4;

    for (int kt = 0; kt < 8; ++kt) {
        const int k0 = kt * 32;
        const float* as = A + (size_t)(bm + ar) * 256 + k0 + akb;
        const float4 a0 = *(const float4*)(as + 0);
        const float4 a1 = *(const float4*)(as + 4);
        const float4 a2 = *(const float4*)(as + 8);
        const float4 a3 = *(const float4*)(as + 12);
        float bv[16];
#pragma unroll
        for (int j = 0; j < 16; ++j)
            bv[j] = W[(size_t)(k0 + bkg + j) * sW + nb + bn_l];

        const half8 ha0 = {(_Float16)a0.x, (_Float16)a0.y, (_Float16)a0.z, (_Float16)a0.w,
                           (_Float16)a1.x, (_Float16)a1.y, (_Float16)a1.z, (_Float16)a1.w};
        const half8 ha1 = {(_Float16)a2.x, (_Float16)a2.y, (_Float16)a2.z, (_Float16)a2.w,
                           (_Float16)a3.x, (_Float16)a3.y, (_Float16)a3.z, (_Float16)a3.w};
        const half8 hb0 = {(_Float16)bv[0], (_Float16)bv[1], (_Float16)bv[2], (_Float16)bv[3],
                           (_Float16)bv[4], (_Float16)bv[5], (_Float16)bv[6], (_Float16)bv[7]};
        const half8 hb1 = {(_Float16)bv[8], (_Float16)bv[9], (_Float16)bv[10], (_Float16)bv[11],
                           (_Float16)bv[12], (_Float16)bv[13], (_Float16)bv[14], (_Float16)bv[15]};

        __syncthreads();   // prior tile's LDS reads complete
        *(half8*)(As + ar * 34 + akb) = ha0;
        *(half8*)(As + ar * 34 + akb + 8) = ha1;
        *(half8*)(Bs + bn_l * 34 + bkg) = hb0;
        *(half8*)(Bs + bn_l * 34 + bkg + 8) = hb1;
        __syncthreads();   // staging visible

        half8 af[4], bf[4];
#pragma unroll
        for (int i = 0; i < 4; ++i)
            af[i] = *(const half8*)(As + (wm + i * 16 + ml) * 34 + kq);
#pragma unroll
        for (int j = 0; j < 4; ++j)
            bf[j] = *(const half8*)(Bs + (wn + j * 16 + ml) * 34 + kq);
#pragma unroll
        for (int i = 0; i < 4; ++i)
#pragma unroll
            for (int j = 0; j < 4; ++j)
                acc[i][j] = __builtin_amdgcn_mfma_f32_16x16x32_f16(af[i], bf[j], acc[i][j], 0, 0, 0);
    }

    const int r0 = (lane >> 4) * 4;
#pragma unroll
    for (int j = 0; j < 4; ++j) {
        const int col = bn + wn + j * 16 + ml;
        const float bj = g1 ? b_val[col] : (col < 256 ? b_off[col] : b_attn[col - 256]);
#pragma unroll
        for (int i = 0; i < 4; ++i) {
            const size_t rbase = (size_t)(bm + wm + i * 16 + r0) * NN + col;
#pragma unroll
            for (int r = 0; r < 4; ++r)
                C[rbase + (size_t)r * NN] = (_Float16)(acc[i][j][r] + bj);
        }
    }
}

// -------- R4 GEMM core (DMA staging, pitch 32) for the final GEMM -------------
__device__ __forceinline__ void gemm_core(
    const _Float16* __restrict__ A, const _Float16* __restrict__ Bt,
    const float* __restrict__ bias, float* __restrict__ Cv,
    int NN, int mt, int nt)
{
    __shared__ _Float16 Ah[128 * 32];
    __shared__ _Float16 Bh[64 * 32];

    const int tid = threadIdx.x;
    const int bm = mt * 128;
    const int bn = nt * 64;
    const int wave = tid >> 6, lane = tid & 63;
    const int wm = (wave & 1) * 64, wn = (wave >> 1) * 32;
    const int ml = lane & 15, kq = (lane >> 4) * 8;
    const int lr = lane >> 2;
    const int lk = (lane & 3) * 8;

    const f32x4 zero4 = {0.f, 0.f, 0.f, 0.f};
    f32x4 acc[4][2];
#pragma unroll
    for (int i = 0; i < 4; ++i)
#pragma unroll
        for (int j = 0; j < 2; ++j) acc[i][j] = zero4;

    for (int kt = 0; kt < 8; ++kt) {
        const int k0 = kt * 32;
        __syncthreads();
#pragma unroll
        for (int t = 0; t < 2; ++t) {
            const int row = wave * 32 + t * 16;
            load_lds16(A + (size_t)(bm + row + lr) * 256 + k0 + lk,
                       Ah + (size_t)row * 32);
        }
        {
            const int row = wave * 16;
            load_lds16(Bt + (size_t)(bn + row + lr) * 256 + k0 + lk,
                       Bh + (size_t)row * 32);
        }
        __syncthreads();

        half8 af[4], bf[2];
#pragma unroll
        for (int i = 0; i < 4; ++i)
            af[i] = *(const half8*)(Ah + (wm + i * 16 + ml) * 32 + kq);
#pragma unroll
        for (int j = 0; j < 2; ++j)
            bf[j] = *(const half8*)(Bh + (wn + j * 16 + ml) * 32 + kq);
#pragma unroll
        for (int i = 0; i < 4; ++i)
#pragma unroll
            for (int j = 0; j < 2; ++j)
                acc[i][j] = __builtin_amdgcn_mfma_f32_16x16x32_f16(af[i], bf[j], acc[i][j], 0, 0, 0);
    }

    const int r0 = (lane >> 4) * 4;
#pragma unroll
    for (int j = 0; j < 2; ++j) {
        const int col = bn + wn + j * 16 + ml;
        const float bj = bias[col];
#pragma unroll
        for (int i = 0; i < 4; ++i) {
            const size_t rbase = (size_t)(bm + wm + i * 16 + r0) * NN + col;
#pragma unroll
            for (int r = 0; r < 4; ++r)
                Cv[rbase + (size_t)r * NN] = acc[i][j][r] + bj;
        }
    }
}

__global__ __launch_bounds__(256) void gemm_single(
    const _Float16* __restrict__ A, const _Float16* __restrict__ Bt,
    const float* __restrict__ bias, float* __restrict__ Cv)
{
    const int id = blockIdx.x;
    gemm_core(A, Bt, bias, Cv, 256, id >> 2, id & 3);
}

// ---------------- sampler: batched-gather ILP version -------------------------
// 1 wave = 2 queries; per level compute all 16 corner (addr,weight) pairs,
// issue 16 half8 loads, then accumulate. launch_bounds(256,4) for VGPR room.
__global__ __launch_bounds__(256, 4) void sample_f16(
    const _Float16* __restrict__ valh,   // [M,256] f16
    const float* __restrict__ refp,      // [B,Lq,4,2]
    const _Float16* __restrict__ offh,   // [M,384] f16: 0-255 offsets, 256-383 logits
    const float* __restrict__ W_out,     // [256,256] f32 (k-major)
    _Float16* __restrict__ wto,          // [256,256] f16 (n-major, k-contig)
    _Float16* __restrict__ acc_out)      // [M,256] f16
{
    // fold W_out transpose into the first 256 blocks (consumed next dispatch)
    if (blockIdx.x < 256)
        wto[blockIdx.x * 256 + threadIdx.x] =
            (_Float16)W_out[threadIdx.x * 256 + blockIdx.x];

    const int wave = threadIdx.x >> 6, lane = threadIdx.x & 63;
    const int q2 = lane >> 5, sl = lane & 31;
    const int bq = blockIdx.x * 8 + wave * 2 + q2;    // 0..21759
    const int b = bq / 5440;
    const int h = sl >> 2;          // head
    const int d8 = (sl & 3) * 8;    // channel octet within head

    const _Float16* off_row = offh + (size_t)bq * 384 + h * 32;
    const _Float16* att_row = offh + (size_t)bq * 384 + 256 + h * 16;
    const float* rp = refp + (size_t)bq * 8;

    const half8 ofr0 = *(const half8*)(off_row);
    const half8 ofr1 = *(const half8*)(off_row + 8);
    const half8 ofr2 = *(const half8*)(off_row + 16);
    const half8 ofr3 = *(const half8*)(off_row + 24);
    float lg[16];
    {
        const half8 t0 = *(const half8*)(att_row);
        const half8 t1 = *(const half8*)(att_row + 8);
#pragma unroll
        for (int j = 0; j < 8; ++j) { lg[j] = (float)t0[j]; lg[8 + j] = (float)t1[j]; }
    }
    float mx = -1e30f;
#pragma unroll
    for (int i = 0; i < 16; ++i) mx = fmaxf(mx, lg[i]);
    float s = 0.f;
#pragma unroll
    for (int i = 0; i < 16; ++i) { lg[i] = __expf(lg[i] - mx); s += lg[i]; }
    const float inv = 1.f / s;

    const float4 rp01 = *(const float4*)rp;
    const float4 rp23 = *(const float4*)(rp + 4);
    const float rxs[4] = {rp01.x, rp01.z, rp23.x, rp23.z};
    const float rys[4] = {rp01.y, rp01.w, rp23.y, rp23.w};

    const int Ws_[4] = {64, 32, 16, 8};
    const int starts_[4] = {0, 4096, 5120, 5376};

    half8 acc = splat8((_Float16)0.f);
#pragma unroll
    for (int l = 0; l < 4; ++l) {
        const int W = Ws_[l];
        const float fW = (float)W;
        const _Float16* vbase = valh + ((size_t)(b * 5440 + starts_[l])) * 256 + h * 32 + d8;
        const float rx = rxs[l], ry = rys[l];

        int idx_[16];
        _Float16 w_[16];
#pragma unroll
        for (int p = 0; p < 4; ++p) {
            const int pi = l * 4 + p;
            const float aw = lg[pi] * inv;
            float ox, oy;
            {
                const half8 src = (pi < 8) ? ((pi < 4) ? ofr0 : ofr1)
                                           : ((pi < 12) ? ofr2 : ofr3);
                const int e = (pi & 3) * 2;
                ox = (float)src[e];
                oy = (float)src[e + 1];
            }
            const float x = fmaf(rx, fW, ox) - 0.5f;
            const float y = fmaf(ry, fW, oy) - 0.5f;
            const float x0f = floorf(x), y0f = floorf(y);
            const int x0 = (int)x0f, y0 = (int)y0f;
            const float wx = x - x0f, wy = y - y0f;
            const bool okx0 = ((unsigned)x0 < (unsigned)W);
            const bool okx1 = ((unsigned)(x0 + 1) < (unsigned)W);
            const bool oky0 = ((unsigned)y0 < (unsigned)W);
            const bool oky1 = ((unsigned)(y0 + 1) < (unsigned)W);
            const int xc0 = min(max(x0, 0), W - 1);
            const int xc1 = min(max(x0 + 1, 0), W - 1);
            const int yc0 = min(max(y0, 0), W - 1);
            const int yc1 = min(max(y0 + 1, 0), W - 1);
            w_[p * 4 + 0] = (_Float16)((okx0 & oky0) ? (1.f - wx) * (1.f - wy) * aw : 0.f);
            w_[p * 4 + 1] = (_Float16)((okx1 & oky0) ? wx * (1.f - wy) * aw : 0.f);
            w_[p * 4 + 2] = (_Float16)((okx0 & oky1) ? (1.f - wx) * wy * aw : 0.f);
            w_[p * 4 + 3] = (_Float16)((okx1 & oky1) ? wx * wy * aw : 0.f);
            idx_[p * 4 + 0] = (yc0 * W + xc0) * 256;
            idx_[p * 4 + 1] = (yc0 * W + xc1) * 256;
            idx_[p * 4 + 2] = (yc1 * W + xc0) * 256;
            idx_[p * 4 + 3] = (yc1 * W + xc1) * 256;
        }

        half8 c_[16];
#pragma unroll
        for (int i = 0; i < 16; ++i)
            c_[i] = *(const half8*)(vbase + idx_[i]);
#pragma unroll
        for (int i = 0; i < 16; ++i)
            acc += c_[i] * splat8(w_[i]);
    }

    *(half8*)(acc_out + (size_t)bq * 256 + h * 32 + d8) = acc;
}

extern "C" void kernel_launch(void* const* d_in, const int* in_sizes, int n_in,
                              void* d_out, int out_size, void* d_ws, size_t ws_size,
                              hipStream_t stream) {
    const float* query  = (const float*)d_in[0];
    const float* refp   = (const float*)d_in[1];
    const float* value  = (const float*)d_in[2];
    const float* W_off  = (const float*)d_in[3];
    const float* b_off  = (const float*)d_in[4];
    const float* W_attn = (const float*)d_in[5];
    const float* b_attn = (const float*)d_in[6];
    const float* W_val  = (const float*)d_in[7];
    const float* b_val  = (const float*)d_in[8];
    const float* W_out  = (const float*)d_in[9];
    const float* b_out  = (const float*)d_in[10];
    float* out = (float*)d_out;

    const size_t M = M_TOTAL;

    _Float16* valh  = (_Float16*)d_ws;                // M*256
    _Float16* offh  = valh + M * 256;                 // M*384
    _Float16* acc16 = offh + M * 384;                 // M*256
    _Float16* wto   = acc16 + M * 256;                // 256*256

    dim3 blk(256);
    gemm12_cvt<<<dim3(850), blk, 0, stream>>>(
        value, query, W_val, W_off, W_attn, b_val, b_off, b_attn, valh, offh);
    sample_f16<<<dim3(M / 8), blk, 0, stream>>>(valh, refp, offh, W_out, wto, acc16);
    gemm_single<<<dim3(680), blk, 0, stream>>>(acc16, wto, b_out, out);
}

// Round 10
// 173.930 us; speedup vs baseline: 1.1447x; 1.0353x over previous
//
#include <hip/hip_runtime.h>

// MSDeformAttn: B=4, Lq=Lv=5440 (M=21760), C=256, heads=8, levels=4, points=4, hd=32
// Level shapes: (64,64),(32,32),(16,16),(8,8) -> starts 0,4096,5120,5376
//
// R9: force the sampler's gather MLP with sched_barrier fences.
//  - R8 post-mortem: c_[16] batch was re-serialized by the scheduler (VGPR
//    stayed 40) -> latency theory untested. valh (11MB) >> per-XCD L2 (4MB),
//    refpoints uniform-random -> ~2/3 gathers at L3 latency; need ~16 loads
//    in flight/wave to hide.
//  - sched_barrier(0) fences: addr-calc | 16 loads | FMAs. Predict VGPR>=100,
//    sampler 49 -> ~35us if latency-bound; unchanged => structural ceiling.
//  - gemm12_cvt (BN=128) and gemm_single byte-identical to R8.

typedef __attribute__((ext_vector_type(8))) _Float16 half8;
typedef __attribute__((ext_vector_type(4))) float f32x4;

typedef __attribute__((address_space(3))) unsigned int lds_uint;
typedef const __attribute__((address_space(1))) unsigned int g_uint;

__device__ __forceinline__ void load_lds16(const _Float16* g, _Float16* l) {
    __builtin_amdgcn_global_load_lds((g_uint*)g, (lds_uint*)l, 16, 0, 0);
}

__device__ __forceinline__ half8 splat8(_Float16 v) {
    half8 r = {v, v, v, v, v, v, v, v};
    return r;
}

#define M_TOTAL 21760

// -------- fused GEMM1+GEMM2 from f32 sources, 128x128 tiles, BK=32 ------------
__global__ __launch_bounds__(256) void gemm12_cvt(
    const float* __restrict__ value, const float* __restrict__ query,
    const float* __restrict__ W_val, const float* __restrict__ W_off,
    const float* __restrict__ W_attn,
    const float* __restrict__ b_val, const float* __restrict__ b_off,
    const float* __restrict__ b_attn,
    _Float16* __restrict__ valh, _Float16* __restrict__ offh)
{
    __shared__ _Float16 As[128 * 34];   // pitch 34 f16 = 17 dwords (coprime 32)
    __shared__ _Float16 Bs[128 * 34];

    const bool g1 = blockIdx.x < 340;
    const int id = g1 ? blockIdx.x : blockIdx.x - 340;
    const int mt = g1 ? (id >> 1) : (id / 3);
    const int nt = g1 ? (id & 1) : (id % 3);
    const int NN = g1 ? 256 : 384;
    const float* A = g1 ? value : query;
    _Float16* C = g1 ? valh : offh;
    const int bm = mt * 128;
    const int bn = nt * 128;

    const float* W;
    int sW, nb;
    if (g1)            { W = W_val;  sW = 256; nb = bn; }
    else if (nt < 2)   { W = W_off;  sW = 256; nb = bn; }
    else               { W = W_attn; sW = 128; nb = 0;  }

    const int tid = threadIdx.x;
    const int wave = tid >> 6, lane = tid & 63;
    const int wm = (wave & 1) * 64, wn = (wave >> 1) * 64;
    const int ml = lane & 15, kq = (lane >> 4) * 8;

    const int ar = tid >> 1, akb = (tid & 1) * 16;
    const int bn_l = tid & 127, bkg = (tid >> 7) * 16;

    const f32x4 zero4 = {0.f, 0.f, 0.f, 0.f};
    f32x4 acc[4][4];
#pragma unroll
    for (int i = 0; i < 4; ++i)
#pragma unroll
        for (int j = 0; j < 4; ++j) acc[i][j] = zero4;

    for (int kt = 0; kt < 8; ++kt) {
        const int k0 = kt * 32;
        const float* as = A + (size_t)(bm + ar) * 256 + k0 + akb;
        const float4 a0 = *(const float4*)(as + 0);
        const float4 a1 = *(const float4*)(as + 4);
        const float4 a2 = *(const float4*)(as + 8);
        const float4 a3 = *(const float4*)(as + 12);
        float bv[16];
#pragma unroll
        for (int j = 0; j < 16; ++j)
            bv[j] = W[(size_t)(k0 + bkg + j) * sW + nb + bn_l];

        const half8 ha0 = {(_Float16)a0.x, (_Float16)a0.y, (_Float16)a0.z, (_Float16)a0.w,
                           (_Float16)a1.x, (_Float16)a1.y, (_Float16)a1.z, (_Float16)a1.w};
        const half8 ha1 = {(_Float16)a2.x, (_Float16)a2.y, (_Float16)a2.z, (_Float16)a2.w,
                           (_Float16)a3.x, (_Float16)a3.y, (_Float16)a3.z, (_Float16)a3.w};
        const half8 hb0 = {(_Float16)bv[0], (_Float16)bv[1], (_Float16)bv[2], (_Float16)bv[3],
                           (_Float16)bv[4], (_Float16)bv[5], (_Float16)bv[6], (_Float16)bv[7]};
        const half8 hb1 = {(_Float16)bv[8], (_Float16)bv[9], (_Float16)bv[10], (_Float16)bv[11],
                           (_Float16)bv[12], (_Float16)bv[13], (_Float16)bv[14], (_Float16)bv[15]};

        __syncthreads();
        *(half8*)(As + ar * 34 + akb) = ha0;
        *(half8*)(As + ar * 34 + akb + 8) = ha1;
        *(half8*)(Bs + bn_l * 34 + bkg) = hb0;
        *(half8*)(Bs + bn_l * 34 + bkg + 8) = hb1;
        __syncthreads();

        half8 af[4], bf[4];
#pragma unroll
        for (int i = 0; i < 4; ++i)
            af[i] = *(const half8*)(As + (wm + i * 16 + ml) * 34 + kq);
#pragma unroll
        for (int j = 0; j < 4; ++j)
            bf[j] = *(const half8*)(Bs + (wn + j * 16 + ml) * 34 + kq);
#pragma unroll
        for (int i = 0; i < 4; ++i)
#pragma unroll
            for (int j = 0; j < 4; ++j)
                acc[i][j] = __builtin_amdgcn_mfma_f32_16x16x32_f16(af[i], bf[j], acc[i][j], 0, 0, 0);
    }

    const int r0 = (lane >> 4) * 4;
#pragma unroll
    for (int j = 0; j < 4; ++j) {
        const int col = bn + wn + j * 16 + ml;
        const float bj = g1 ? b_val[col] : (col < 256 ? b_off[col] : b_attn[col - 256]);
#pragma unroll
        for (int i = 0; i < 4; ++i) {
            const size_t rbase = (size_t)(bm + wm + i * 16 + r0) * NN + col;
#pragma unroll
            for (int r = 0; r < 4; ++r)
                C[rbase + (size_t)r * NN] = (_Float16)(acc[i][j][r] + bj);
        }
    }
}

// -------- R4 GEMM core (DMA staging, pitch 32) for the final GEMM -------------
__device__ __forceinline__ void gemm_core(
    const _Float16* __restrict__ A, const _Float16* __restrict__ Bt,
    const float* __restrict__ bias, float* __restrict__ Cv,
    int NN, int mt, int nt)
{
    __shared__ _Float16 Ah[128 * 32];
    __shared__ _Float16 Bh[64 * 32];

    const int tid = threadIdx.x;
    const int bm = mt * 128;
    const int bn = nt * 64;
    const int wave = tid >> 6, lane = tid & 63;
    const int wm = (wave & 1) * 64, wn = (wave >> 1) * 32;
    const int ml = lane & 15, kq = (lane >> 4) * 8;
    const int lr = lane >> 2;
    const int lk = (lane & 3) * 8;

    const f32x4 zero4 = {0.f, 0.f, 0.f, 0.f};
    f32x4 acc[4][2];
#pragma unroll
    for (int i = 0; i < 4; ++i)
#pragma unroll
        for (int j = 0; j < 2; ++j) acc[i][j] = zero4;

    for (int kt = 0; kt < 8; ++kt) {
        const int k0 = kt * 32;
        __syncthreads();
#pragma unroll
        for (int t = 0; t < 2; ++t) {
            const int row = wave * 32 + t * 16;
            load_lds16(A + (size_t)(bm + row + lr) * 256 + k0 + lk,
                       Ah + (size_t)row * 32);
        }
        {
            const int row = wave * 16;
            load_lds16(Bt + (size_t)(bn + row + lr) * 256 + k0 + lk,
                       Bh + (size_t)row * 32);
        }
        __syncthreads();

        half8 af[4], bf[2];
#pragma unroll
        for (int i = 0; i < 4; ++i)
            af[i] = *(const half8*)(Ah + (wm + i * 16 + ml) * 32 + kq);
#pragma unroll
        for (int j = 0; j < 2; ++j)
            bf[j] = *(const half8*)(Bh + (wn + j * 16 + ml) * 32 + kq);
#pragma unroll
        for (int i = 0; i < 4; ++i)
#pragma unroll
            for (int j = 0; j < 2; ++j)
                acc[i][j] = __builtin_amdgcn_mfma_f32_16x16x32_f16(af[i], bf[j], acc[i][j], 0, 0, 0);
    }

    const int r0 = (lane >> 4) * 4;
#pragma unroll
    for (int j = 0; j < 2; ++j) {
        const int col = bn + wn + j * 16 + ml;
        const float bj = bias[col];
#pragma unroll
        for (int i = 0; i < 4; ++i) {
            const size_t rbase = (size_t)(bm + wm + i * 16 + r0) * NN + col;
#pragma unroll
            for (int r = 0; r < 4; ++r)
                Cv[rbase + (size_t)r * NN] = acc[i][j][r] + bj;
        }
    }
}

__global__ __launch_bounds__(256) void gemm_single(
    const _Float16* __restrict__ A, const _Float16* __restrict__ Bt,
    const float* __restrict__ bias, float* __restrict__ Cv)
{
    const int id = blockIdx.x;
    gemm_core(A, Bt, bias, Cv, 256, id >> 2, id & 3);
}

// ---------------- sampler: batched gathers, schedule pinned -------------------
__global__ __launch_bounds__(256, 4) void sample_f16(
    const _Float16* __restrict__ valh,   // [M,256] f16
    const float* __restrict__ refp,      // [B,Lq,4,2]
    const _Float16* __restrict__ offh,   // [M,384] f16: 0-255 offsets, 256-383 logits
    const float* __restrict__ W_out,     // [256,256] f32 (k-major)
    _Float16* __restrict__ wto,          // [256,256] f16 (n-major, k-contig)
    _Float16* __restrict__ acc_out)      // [M,256] f16
{
    // fold W_out transpose into the first 256 blocks (consumed next dispatch)
    if (blockIdx.x < 256)
        wto[blockIdx.x * 256 + threadIdx.x] =
            (_Float16)W_out[threadIdx.x * 256 + blockIdx.x];

    const int wave = threadIdx.x >> 6, lane = threadIdx.x & 63;
    const int q2 = lane >> 5, sl = lane & 31;
    const int bq = blockIdx.x * 8 + wave * 2 + q2;    // 0..21759
    const int b = bq / 5440;
    const int h = sl >> 2;          // head
    const int d8 = (sl & 3) * 8;    // channel octet within head

    const _Float16* off_row = offh + (size_t)bq * 384 + h * 32;
    const _Float16* att_row = offh + (size_t)bq * 384 + 256 + h * 16;
    const float* rp = refp + (size_t)bq * 8;

    const half8 ofr0 = *(const half8*)(off_row);
    const half8 ofr1 = *(const half8*)(off_row + 8);
    const half8 ofr2 = *(const half8*)(off_row + 16);
    const half8 ofr3 = *(const half8*)(off_row + 24);
    float lg[16];
    {
        const half8 t0 = *(const half8*)(att_row);
        const half8 t1 = *(const half8*)(att_row + 8);
#pragma unroll
        for (int j = 0; j < 8; ++j) { lg[j] = (float)t0[j]; lg[8 + j] = (float)t1[j]; }
    }
    float mx = -1e30f;
#pragma unroll
    for (int i = 0; i < 16; ++i) mx = fmaxf(mx, lg[i]);
    float s = 0.f;
#pragma unroll
    for (int i = 0; i < 16; ++i) { lg[i] = __expf(lg[i] - mx); s += lg[i]; }
    const float inv = 1.f / s;

    const float4 rp01 = *(const float4*)rp;
    const float4 rp23 = *(const float4*)(rp + 4);
    const float rxs[4] = {rp01.x, rp01.z, rp23.x, rp23.z};
    const float rys[4] = {rp01.y, rp01.w, rp23.y, rp23.w};

    const int Ws_[4] = {64, 32, 16, 8};
    const int starts_[4] = {0, 4096, 5120, 5376};

    half8 acc = splat8((_Float16)0.f);
#pragma unroll
    for (int l = 0; l < 4; ++l) {
        const int W = Ws_[l];
        const float fW = (float)W;
        const _Float16* vbase = valh + ((size_t)(b * 5440 + starts_[l])) * 256 + h * 32 + d8;
        const float rx = rxs[l], ry = rys[l];

        int idx_[16];
        _Float16 w_[16];
#pragma unroll
        for (int p = 0; p < 4; ++p) {
            const int pi = l * 4 + p;
            const float aw = lg[pi] * inv;
            float ox, oy;
            {
                const half8 src = (pi < 8) ? ((pi < 4) ? ofr0 : ofr1)
                                           : ((pi < 12) ? ofr2 : ofr3);
                const int e = (pi & 3) * 2;
                ox = (float)src[e];
                oy = (float)src[e + 1];
            }
            const float x = fmaf(rx, fW, ox) - 0.5f;
            const float y = fmaf(ry, fW, oy) - 0.5f;
            const float x0f = floorf(x), y0f = floorf(y);
            const int x0 = (int)x0f, y0 = (int)y0f;
            const float wx = x - x0f, wy = y - y0f;
            const bool okx0 = ((unsigned)x0 < (unsigned)W);
            const bool okx1 = ((unsigned)(x0 + 1) < (unsigned)W);
            const bool oky0 = ((unsigned)y0 < (unsigned)W);
            const bool oky1 = ((unsigned)(y0 + 1) < (unsigned)W);
            const int xc0 = min(max(x0, 0), W - 1);
            const int xc1 = min(max(x0 + 1, 0), W - 1);
            const int yc0 = min(max(y0, 0), W - 1);
            const int yc1 = min(max(y0 + 1, 0), W - 1);
            w_[p * 4 + 0] = (_Float16)((okx0 & oky0) ? (1.f - wx) * (1.f - wy) * aw : 0.f);
            w_[p * 4 + 1] = (_Float16)((okx1 & oky0) ? wx * (1.f - wy) * aw : 0.f);
            w_[p * 4 + 2] = (_Float16)((okx0 & oky1) ? (1.f - wx) * wy * aw : 0.f);
            w_[p * 4 + 3] = (_Float16)((okx1 & oky1) ? wx * wy * aw : 0.f);
            idx_[p * 4 + 0] = (yc0 * W + xc0) * 256;
            idx_[p * 4 + 1] = (yc0 * W + xc1) * 256;
            idx_[p * 4 + 2] = (yc1 * W + xc0) * 256;
            idx_[p * 4 + 3] = (yc1 * W + xc1) * 256;
        }

        // pin: all 16 loads issue before any consumer (progressive vmcnt drain)
        __builtin_amdgcn_sched_barrier(0);
        half8 c_[16];
#pragma unroll
        for (int i = 0; i < 16; ++i)
            c_[i] = *(const half8*)(vbase + idx_[i]);
        __builtin_amdgcn_sched_barrier(0);
#pragma unroll
        for (int i = 0; i < 16; ++i)
            acc += c_[i] * splat8(w_[i]);
    }

    *(half8*)(acc_out + (size_t)bq * 256 + h * 32 + d8) = acc;
}

extern "C" void kernel_launch(void* const* d_in, const int* in_sizes, int n_in,
                              void* d_out, int out_size, void* d_ws, size_t ws_size,
                              hipStream_t stream) {
    const float* query  = (const float*)d_in[0];
    const float* refp   = (const float*)d_in[1];
    const float* value  = (const float*)d_in[2];
    const float* W_off  = (const float*)d_in[3];
    const float* b_off  = (const float*)d_in[4];
    const float* W_attn = (const float*)d_in[5];
    const float* b_attn = (const float*)d_in[6];
    const float* W_val  = (const float*)d_in[7];
    const float* b_val  = (const float*)d_in[8];
    const float* W_out  = (const float*)d_in[9];
    const float* b_out  = (const float*)d_in[10];
    float* out = (float*)d_out;

    const size_t M = M_TOTAL;

    _Float16* valh  = (_Float16*)d_ws;                // M*256
    _Float16* offh  = valh + M * 256;                 // M*384
    _Float16* acc16 = offh + M * 384;                 // M*256
    _Float16* wto   = acc16 + M * 256;                // 256*256

    dim3 blk(256);
    gemm12_cvt<<<dim3(850), blk, 0, stream>>>(
        value, query, W_val, W_off, W_attn, b_val, b_off, b_attn, valh, offh);
    sample_f16<<<dim3(M / 8), blk, 0, stream>>>(valh, refp, offh, W_out, wto, acc16);
    gemm_single<<<dim3(680), blk, 0, stream>>>(acc16, wto, b_out, out);
}